// Round 13
// baseline (176.288 us; speedup 1.0000x reference)
//
#include <hip/hip_runtime.h>

// CG tensor-product iteration: per sample n, 34 (l1,l2,L) combos of
//   b[n,M,p,q] = sum_{i,j} x1_{l1}[n,i,p] * x2_{l2}[n,j,q] * C[i,j,M]
// packed into a (n, 39936) f32 row, keys (L,S) sorted, blocks concatenated.
//
// R1 scatter == R3 staged == R11 linear-front == 164-169us -> write pattern
// irrelevant. Instrumented rounds show ~110us of real VALU time -> kernel is
// VALU/write balanced, poorly overlapped. This round: factorize the einsum
//   T[i,M,q] = sum_j C[i,j,M] * x2[j,q]   (once per sample, in LDS)
//   b[M,p,q] = sum_i x1[i,p] * T[i,M,q]
// cutting FMAs/sample 880K -> 199K. Stores stay R1-style direct scatter.
// (R12 fix: padded T stride is 1028, not 796 -> LDS 67.8KB, 2 blocks/CU.)

namespace {

typedef float f32x4 __attribute__((ext_vector_type(4)));

constexpr int NC = 34;
constexpr int TSTR = 1028;  // T floats per q (= sum_c D1*DLpad), stride

struct CInfo { int l1, l2, L, pbase2, outbase, mstride, tb, ofs; };
struct CTable { CInfo c[NC]; int packed2; int outsize; int ttotal; };

constexpr CTable build_table() {
  CTable t{};
  int nb[4][2] = {};
  for (int l1 = 0; l1 < 4; ++l1)
    for (int l2 = 0; l2 < 4; ++l2) {
      int lo = l1 > l2 ? l1 - l2 : l2 - l1;
      int hi = (l1 + l2 < 3) ? l1 + l2 : 3;
      for (int L = lo; L <= hi; ++L)
        nb[L][((l1 + l2 + L) & 1) ? 0 : 1]++;
    }
  int keyoff[4][2] = {};
  int off = 0;
  for (int L = 0; L < 4; ++L)
    for (int s = 0; s < 2; ++s) {
      keyoff[L][s] = off;
      off += (2 * L + 1) * 256 * nb[L][s];
    }
  t.outsize = off;
  int blk[4][2] = {};
  int idx = 0, pb2 = 0, tb = 0, fill = 0;
  for (int l1 = 0; l1 < 4; ++l1)
    for (int l2 = 0; l2 < 4; ++l2) {
      int lo = l1 > l2 ? l1 - l2 : l2 - l1;
      int hi = (l1 + l2 < 3) ? l1 + l2 : 3;
      for (int L = lo; L <= hi; ++L) {
        int s = ((l1 + l2 + L) & 1) ? 0 : 1;
        int D1 = 2 * l1 + 1, D2 = 2 * l2 + 1, DL = 2 * L + 1;
        int DP = (DL + 3) & ~3;
        t.c[idx].l1 = l1; t.c[idx].l2 = l2; t.c[idx].L = L;
        t.c[idx].pbase2 = pb2;
        t.c[idx].outbase = keyoff[L][s] + blk[L][s] * 256;
        t.c[idx].mstride = 256 * nb[L][s];
        t.c[idx].tb = tb;
        // greedy step-1 thread-slot packing: combo occupies [ofs, ofs+D1*16)
        if (fill + D1 * 16 > 256) fill = 0;
        t.c[idx].ofs = fill;
        fill += D1 * 16;
        blk[L][s]++;
        pb2 += D1 * D2 * DP;
        tb += D1 * DP;
        ++idx;
      }
    }
  t.packed2 = pb2;
  t.ttotal = tb;
  return t;
}

constexpr CTable CTAB = build_table();
static_assert(CTAB.outsize == 39936, "output layout mismatch");
static_assert(CTAB.ttotal == TSTR, "T stride mismatch");
static_assert(CTAB.packed2 <= 8192, "packed cg exceeds 32KB");

// ---- coefficient pre-pack: cg[l1,l2,L,i,j,M] -> cgp2[pbase2 + (i*D2+j)*DP + M]
template <int CI>
__device__ __forceinline__ void pack_combo(const float* __restrict__ cg,
                                           float* __restrict__ cgp2, int tid) {
  if constexpr (CI < NC) {
    constexpr CInfo c = CTAB.c[CI];
    constexpr int D2 = 2 * c.l2 + 1, DL = 2 * c.L + 1;
    constexpr int DP = (DL + 3) & ~3;
    constexpr int SZ = (2 * c.l1 + 1) * D2 * DL;
    for (int tt = tid; tt < SZ; tt += 256) {
      int M = tt % DL, ij = tt / DL;
      int j = ij % D2, i = ij / D2;
      cgp2[c.pbase2 + ij * DP + M] =
          cg[((((c.l1 * 4 + c.l2) * 4 + c.L) * 7 + i) * 7 + j) * 7 + M];
    }
    pack_combo<CI + 1>(cg, cgp2, tid);
  }
}

__global__ void pack_cg_kernel(const float* __restrict__ cg,
                               float* __restrict__ cgp2) {
  // zero pad slots first so unwritten lanes hold finite values
  for (int i = (int)threadIdx.x; i < CTAB.packed2; i += 256) cgp2[i] = 0.f;
  __syncthreads();
  pack_combo<0>(cg, cgp2, (int)threadIdx.x);
}

// ---- step 1: T[q*TSTR + tb + i*DP + M] = sum_j C[i,j,M] * x2s[R2+j][q]
template <int CI>
__device__ __forceinline__ void step1(const float* __restrict__ cgp2,
                                      const float* __restrict__ x2s,
                                      float* __restrict__ T, int tid) {
  if constexpr (CI < NC) {
    constexpr CInfo c = CTAB.c[CI];
    constexpr int D1 = 2 * c.l1 + 1, D2 = 2 * c.l2 + 1, DL = 2 * c.L + 1;
    constexpr int DP = (DL + 3) & ~3;
    constexpr int R2 = c.l2 * c.l2;
    const unsigned d = (unsigned)(tid - c.ofs) & 255u;
    if (d < (unsigned)(D1 * 16)) {
      const int i = (int)(d >> 4), q = (int)(d & 15u);
      float acc[DL];
#pragma unroll
      for (int M = 0; M < DL; ++M) acc[M] = 0.f;
#pragma unroll
      for (int j = 0; j < D2; ++j) {
        const float xv = x2s[(R2 + j) * 16 + q];
        const f32x4 k0 = *reinterpret_cast<const f32x4*>(
            cgp2 + c.pbase2 + (i * D2 + j) * DP);
        f32x4 k1{};
        if constexpr (DP == 8)
          k1 = *reinterpret_cast<const f32x4*>(cgp2 + c.pbase2 +
                                               (i * D2 + j) * DP + 4);
#pragma unroll
        for (int M = 0; M < DL; ++M) {
          const float cc = (M < 4) ? k0[M & 3] : k1[M & 3];
          acc[M] = fmaf(cc, xv, acc[M]);
        }
      }
      float* tp = T + q * TSTR + c.tb + i * DP;
      f32x4 w0;
      w0[0] = acc[0];
      w0[1] = (DL > 1) ? acc[1 < DL ? 1 : 0] : 0.f;
      w0[2] = (DL > 2) ? acc[2 < DL ? 2 : 0] : 0.f;
      w0[3] = (DL > 3) ? acc[3 < DL ? 3 : 0] : 0.f;
      *reinterpret_cast<f32x4*>(tp) = w0;
      if constexpr (DP == 8) {
        f32x4 w1;
        w1[0] = acc[4 < DL ? 4 : 0];
        w1[1] = (DL > 5) ? acc[5 < DL ? 5 : 0] : 0.f;
        w1[2] = (DL > 6) ? acc[6 < DL ? 6 : 0] : 0.f;
        w1[3] = 0.f;
        *reinterpret_cast<f32x4*>(tp + 4) = w1;
      }
    }
    step1<CI + 1>(cgp2, x2s, T, tid);
  }
}

// ---- step 2: b[M,p,q] = sum_i x1r[R1+i] * T[i,M,q]; direct scatter stores.
template <int CI>
__device__ __forceinline__ void step2(const float* __restrict__ Tq,
                                      const float (&x1r)[16],
                                      float* __restrict__ outn) {
  if constexpr (CI < NC) {
    constexpr CInfo c = CTAB.c[CI];
    constexpr int D1 = 2 * c.l1 + 1, DL = 2 * c.L + 1;
    constexpr int DP = (DL + 3) & ~3;
    constexpr int R1 = c.l1 * c.l1;
    float acc[DL];
#pragma unroll
    for (int M = 0; M < DL; ++M) acc[M] = 0.f;
#pragma unroll
    for (int i = 0; i < D1; ++i) {
      const f32x4 t0 = *reinterpret_cast<const f32x4*>(Tq + c.tb + i * DP);
      f32x4 t1{};
      if constexpr (DP == 8)
        t1 = *reinterpret_cast<const f32x4*>(Tq + c.tb + i * DP + 4);
      const float a = x1r[R1 + i];
#pragma unroll
      for (int M = 0; M < DL; ++M) {
        const float tv = (M < 4) ? t0[M & 3] : t1[M & 3];
        acc[M] = fmaf(a, tv, acc[M]);
      }
    }
#pragma unroll
    for (int M = 0; M < DL; ++M)
      outn[c.outbase + M * c.mstride] = acc[M];
    step2<CI + 1>(Tq, x1r, outn);
  }
}

__global__ __launch_bounds__(256) void cg_main(
    const float* __restrict__ x1_0, const float* __restrict__ x2_0,
    const float* __restrict__ x1_1, const float* __restrict__ x2_1,
    const float* __restrict__ x1_2, const float* __restrict__ x2_2,
    const float* __restrict__ x1_3, const float* __restrict__ x2_3,
    const float* __restrict__ cgp2_, float* __restrict__ out) {
  const float* cgp2 = (const float*)__builtin_assume_aligned(cgp2_, 256);
  // LDS: x1s[256] + x2s[256] + T[16*TSTR]  (67.8KB -> 2 blocks/CU)
  __shared__ __align__(16) float lds[512 + 16 * TSTR];
  float* x1s = lds;
  float* x2s = lds + 256;
  float* T = lds + 512;
  const int tid = (int)threadIdx.x;
  const int n = (int)blockIdx.x;
  const int r = tid >> 4, col = tid & 15;
  // stage this sample's 2*256 input floats
  {
    const float* s1; const float* s2; int ri;
    if (r < 1)      { s1 = x1_0 + n * 16;  s2 = x2_0 + n * 16;  ri = r; }
    else if (r < 4) { s1 = x1_1 + n * 48;  s2 = x2_1 + n * 48;  ri = r - 1; }
    else if (r < 9) { s1 = x1_2 + n * 80;  s2 = x2_2 + n * 80;  ri = r - 4; }
    else            { s1 = x1_3 + n * 112; s2 = x2_3 + n * 112; ri = r - 9; }
    x1s[r * 16 + col] = s1[ri * 16 + col];
    x2s[r * 16 + col] = s2[ri * 16 + col];
  }
  __syncthreads();
  // step 1: build T (dense greedy-packed thread slots)
  step1<0>(cgp2, x2s, T, tid);
  __syncthreads();
  // hoist x1 columns (p = r) into registers
  float x1r[16];
#pragma unroll
  for (int k = 0; k < 16; ++k) x1r[k] = x1s[k * 16 + r];
  const float* Tq = T + col * TSTR;  // q = col
  float* outn = out + (size_t)n * (size_t)CTAB.outsize + tid;
  step2<0>(Tq, x1r, outn);
}

}  // namespace

extern "C" void kernel_launch(void* const* d_in, const int* in_sizes, int n_in,
                              void* d_out, int out_size, void* d_ws,
                              size_t ws_size, hipStream_t stream) {
  const float* x1[4];
  const float* x2[4];
  // setup_inputs() dict order is interleaved (x1_l0, x2_l0, x1_l1, ...);
  // detect vs grouped (x1_l0..x1_l3, x2_l0..) via sizes.
  if (in_sizes[1] == in_sizes[0]) {
    for (int l = 0; l < 4; ++l) {
      x1[l] = (const float*)d_in[2 * l];
      x2[l] = (const float*)d_in[2 * l + 1];
    }
  } else {
    for (int l = 0; l < 4; ++l) {
      x1[l] = (const float*)d_in[l];
      x2[l] = (const float*)d_in[4 + l];
    }
  }
  const float* cg = (const float*)d_in[8];
  float* out = (float*)d_out;
  float* cgp2 = (float*)d_ws;  // DL-padded packed coefficients (~19 KB)

  const int n = in_sizes[0] / 16;  // x?_l0 is (n, 1, 16)

  pack_cg_kernel<<<1, 256, 0, stream>>>(cg, cgp2);
  cg_main<<<n, 256, 0, stream>>>(x1[0], x2[0], x1[1], x2[1], x1[2], x2[2],
                                 x1[3], x2[3], cgp2, out);
}